// Round 2
// baseline (235.733 us; speedup 1.0000x reference)
//
#include <hip/hip_runtime.h>
#include <hip/hip_bf16.h>

#define D 128
#define K 64
#define ROWPAD 136   // bf16 elements per LDS row: 128 + 4-float pad -> breaks bank conflicts

typedef __attribute__((ext_vector_type(8))) short short8;   // 8 bf16 in 4 VGPRs
typedef __attribute__((ext_vector_type(4))) short short4v;  // 8 B
typedef __attribute__((ext_vector_type(4))) float f32x4;

// round-to-nearest-even float -> bf16 bits (inputs finite)
__device__ inline short f2bf(float f) {
  union { float f; unsigned u; } v; v.f = f;
  unsigned u = v.u;
  return (short)((u + 0x7fffu + ((u >> 16) & 1u)) >> 16);
}

// ws layout (floats): [0..16) accumulator; [16..80) mnorm[64]; [128..) bf16(2*m) as 8192 shorts
__global__ void prep_kernel(const float* __restrict__ m, float* ws) {
  // grid 64 blocks x 64 threads: block j handles m row j
  const int j = blockIdx.x;
  const int t = threadIdx.x;
  float a0 = m[j * D + t * 2];
  float a1 = m[j * D + t * 2 + 1];
  short* mb = (short*)(ws + 128);
  mb[j * D + t * 2]     = f2bf(2.0f * a0);
  mb[j * D + t * 2 + 1] = f2bf(2.0f * a1);
  float s = a0 * a0 + a1 * a1;
  for (int off = 1; off < 64; off <<= 1) s += __shfl_xor(s, off, 64);
  if (t == 0) ws[16 + j] = s;
  if (j == 0 && t < 16) ws[t] = 0.0f;
}

__launch_bounds__(256)
__global__ void main_kernel(const float* __restrict__ x, float* ws, int nTiles) {
  __shared__ short xs[64 * ROWPAD];   // 64-row bf16 tile, padded
  const float* mnorm = ws + 16;
  const short* mb = (const short*)(ws + 128);
  const int tid  = threadIdx.x;
  const int lane = tid & 63;
  const int wv   = tid >> 6;          // wave 0..3 -> rows wv*16..+15
  const int lid  = lane & 15;         // MFMA: A row / C/D col (j)
  const int quad = lane >> 4;         // A k-group; C/D row = quad*4+reg

  // Full m in registers per wave: 4 j-tiles x 4 k-steps (64 VGPRs)
  short8 bfr[4][4];
  float mn[4];
#pragma unroll
  for (int jt = 0; jt < 4; ++jt) {
    mn[jt] = mnorm[jt * 16 + lid];
#pragma unroll
    for (int kk = 0; kk < 4; ++kk)
      bfr[jt][kk] = *(const short8*)(mb + (jt * 16 + lid) * D + kk * 32 + quad * 8);
  }

  float hacc = 0.f;

  // Prefetch tile blockIdx.x: fully coalesced (256 lanes x float4 = 4 KB/instr)
  f32x4 v[8];
  int t = blockIdx.x;
  if (t < nTiles) {
    const f32x4* xt = (const f32x4*)(x + (size_t)t * (64 * D));
#pragma unroll
    for (int i = 0; i < 8; ++i) v[i] = xt[i * 256 + tid];
  }

  while (t < nTiles) {
    // Stage to LDS as bf16 (padded rows)
#pragma unroll
    for (int i = 0; i < 8; ++i) {
      int f = (i * 256 + tid) * 4;          // float index within 64x128 tile
      int row = f >> 7, col = f & 127;
      short4v p;
      p[0] = f2bf(v[i][0]); p[1] = f2bf(v[i][1]);
      p[2] = f2bf(v[i][2]); p[3] = f2bf(v[i][3]);
      *(short4v*)(xs + row * ROWPAD + col) = p;
    }
    __syncthreads();

    // Prefetch next tile while we compute this one
    int tn = t + gridDim.x;
    if (tn < nTiles) {
      const f32x4* xt = (const f32x4*)(x + (size_t)tn * (64 * D));
#pragma unroll
      for (int i = 0; i < 8; ++i) v[i] = xt[i * 256 + tid];
    }

    // A fragments from LDS: row = wv*16+lid, k = kk*32 + quad*8 .. +8
    const short* xw = xs + (wv * 16 + lid) * ROWPAD + quad * 8;
    short8 a[4];
#pragma unroll
    for (int kk = 0; kk < 4; ++kk) a[kk] = *(const short8*)(xw + kk * 32);

    f32x4 acc[4];
#pragma unroll
    for (int jt = 0; jt < 4; ++jt) acc[jt] = (f32x4){0.f, 0.f, 0.f, 0.f};
#pragma unroll
    for (int kk = 0; kk < 4; ++kk)
#pragma unroll
      for (int jt = 0; jt < 4; ++jt)
        acc[jt] = __builtin_amdgcn_mfma_f32_16x16x32_bf16(a[kk], bfr[jt][kk], acc[jt], 0, 0, 0);

    // Epilogue: scores bounded (|2 x.m| <= 2||x|| ~ 30 << 88) -> no max pass.
    // H = ln(S0) - S1/S0, S0 = sum e^s, S1 = sum s e^s (shift-invariant form).
#pragma unroll
    for (int r = 0; r < 4; ++r) {
      float s0 = acc[0][r] - mn[0];
      float s1 = acc[1][r] - mn[1];
      float s2 = acc[2][r] - mn[2];
      float s3 = acc[3][r] - mn[3];
      float e0 = __expf(s0), e1 = __expf(s1), e2 = __expf(s2), e3 = __expf(s3);
      float S0 = (e0 + e1) + (e2 + e3);
      float S1 = fmaf(s0, e0, fmaf(s1, e1, fmaf(s2, e2, s3 * e3)));
      for (int off = 1; off < 16; off <<= 1) {
        S0 += __shfl_xor(S0, off, 64);
        S1 += __shfl_xor(S1, off, 64);
      }
      float H = __logf(S0) - S1 / S0;
      if (lid == 0) hacc += H;   // one lane per quad group owns row quad*4+r
    }
    __syncthreads();   // protect xs before next staging pass
    t = tn;
  }

  // wave reduce -> block reduce -> one atomic per block
  for (int off = 1; off < 64; off <<= 1) hacc += __shfl_xor(hacc, off, 64);
  __shared__ float red[4];
  if (lane == 0) red[wv] = hacc;
  __syncthreads();
  if (tid == 0) atomicAdd(ws, red[0] + red[1] + red[2] + red[3]);
}

__global__ void final_kernel(const float* __restrict__ m, const float* ws, float* out, int nRows) {
  __shared__ float mu[D];
  int lane = threadIdx.x;  // 64 threads
  for (int d = lane; d < D; d += 64) {
    float s = 0.f;
    for (int j = 0; j < K; ++j) s += m[j * D + d];
    mu[d] = s * (1.0f / K);
  }
  __syncthreads();
  const float* mr = m + lane * D;
  float dot = 0.f;
  for (int d = 0; d < D; ++d) dot += mu[d] * mr[d];
  float s = 2.f * dot - ws[16 + lane];  // shift-invariant: drop ||mu||^2
  float e = __expf(s - 20.f);           // safe shift to avoid overflow paranoia
  float t = s - 20.f;
  float S0 = e, S1 = t * e;
  for (int off = 1; off < 64; off <<= 1) {
    S0 += __shfl_xor(S0, off, 64);
    S1 += __shfl_xor(S1, off, 64);
  }
  float inter = __logf(S0) - S1 / S0;
  if (lane == 0) {
    float intra = ws[0] / (float)nRows;
    out[0] = intra - inter;  // LAMB = 1
    out[1] = intra;
    out[2] = inter;
  }
}

extern "C" void kernel_launch(void* const* d_in, const int* in_sizes, int n_in,
                              void* d_out, int out_size, void* d_ws, size_t ws_size,
                              hipStream_t stream) {
  const float* x = (const float*)d_in[0];
  const float* m = (const float*)d_in[1];
  float* ws = (float*)d_ws;
  float* out = (float*)d_out;
  const int N = in_sizes[0] / D;     // 262144
  const int nTiles = N / 64;         // 4096 tiles of 64 rows

  prep_kernel<<<64, 64, 0, stream>>>(m, ws);

  const int blocks = 2048;           // grid-stride: 2 tiles/block, 1 prefetch deep
  main_kernel<<<blocks, 256, 0, stream>>>(x, ws, nTiles);

  final_kernel<<<1, 64, 0, stream>>>(m, ws, out, N);
}

// Round 3
// 221.622 us; speedup vs baseline: 1.0637x; 1.0637x over previous
//
#include <hip/hip_runtime.h>
#include <hip/hip_bf16.h>

#define D 128
#define K 64
#define MROW 136   // LDS row stride in shorts: 128 + 8 pad -> b-frag reads hit the 8-cyc bank floor

typedef __attribute__((ext_vector_type(8))) short short8;   // 8 bf16 in 4 VGPRs
typedef __attribute__((ext_vector_type(4))) float f32x4;

// round-to-nearest-even float -> bf16 bits (inputs finite)
__device__ inline short f2bf(float f) {
  union { float f; unsigned u; } v; v.f = f;
  unsigned u = v.u;
  return (short)((u + 0x7fffu + ((u >> 16) & 1u)) >> 16);
}

// ws layout (floats): [0..16) accumulator; [16..80) mnorm[64]; [128..) bf16(2*m) as 8192 shorts
__global__ void prep_kernel(const float* __restrict__ m, float* ws) {
  // 64 blocks x 64 threads: block j handles m row j
  const int j = blockIdx.x;
  const int t = threadIdx.x;
  float a0 = m[j * D + t * 2];
  float a1 = m[j * D + t * 2 + 1];
  short* mb = (short*)(ws + 128);
  mb[j * D + t * 2]     = f2bf(2.0f * a0);
  mb[j * D + t * 2 + 1] = f2bf(2.0f * a1);
  float s = a0 * a0 + a1 * a1;
  for (int off = 1; off < 64; off <<= 1) s += __shfl_xor(s, off, 64);
  if (t == 0) ws[16 + j] = s;
  if (j == 0 && t < 16) ws[t] = 0.0f;
}

// m in LDS; each wave = independent stream over contiguous 16-row tiles;
// no barriers in the loop -> no vmcnt(0) drain; pipelined: convert t, issue t+1, compute t.
__launch_bounds__(256, 4)
__global__ void main_kernel(const float* __restrict__ x, float* ws, int tilesPerWave) {
  __shared__ short ms[64 * MROW];
  const float* mnorm = ws + 16;
  const short* mb = (const short*)(ws + 128);
  const int tid  = threadIdx.x;
  const int lane = tid & 63;
  const int wv   = tid >> 6;
  const int lid  = lane & 15;   // A row / C-D col (j)
  const int quad = lane >> 4;   // A k-group; C/D row = quad*4+reg

  const int wave = blockIdx.x * 4 + wv;
  const int base = wave * tilesPerWave;

  // Issue tile-0 x loads FIRST (longest latency), then stage m while they fly.
  f32x4 v[8];
  {
    const float* xb = x + (size_t)(base * 16 + lid) * D + quad * 8;
#pragma unroll
    for (int kk = 0; kk < 4; ++kk) {
      v[2 * kk]     = *(const f32x4*)(xb + kk * 32);
      v[2 * kk + 1] = *(const f32x4*)(xb + kk * 32 + 4);
    }
  }

  // Stage bf16(2*m) into padded LDS: thread copies 4x 16B chunks (col%8==0, row-safe)
#pragma unroll
  for (int i = 0; i < 4; ++i) {
    int g = i * 2048 + tid * 8;           // short index in 64x128
    int row = g >> 7, col = g & 127;
    *(short8*)(ms + row * MROW + col) = *(const short8*)(mb + g);
  }
  float mn[4];
#pragma unroll
  for (int jt = 0; jt < 4; ++jt) mn[jt] = mnorm[jt * 16 + lid];
  __syncthreads();   // the only block-wide barrier

  float hacc = 0.f;

  for (int it = 0; it < tilesPerWave; ++it) {
    // Convert current tile's registers to A fragments (frees v)
    short8 a[4];
#pragma unroll
    for (int kk = 0; kk < 4; ++kk) {
      f32x4 v0 = v[2 * kk], v1 = v[2 * kk + 1];
      short8 av;
      av[0] = f2bf(v0[0]); av[1] = f2bf(v0[1]); av[2] = f2bf(v0[2]); av[3] = f2bf(v0[3]);
      av[4] = f2bf(v1[0]); av[5] = f2bf(v1[1]); av[6] = f2bf(v1[2]); av[7] = f2bf(v1[3]);
      a[kk] = av;
    }

    // Issue next tile's loads now; they stay in flight through MFMA + epilogue
    if (it + 1 < tilesPerWave) {
      const float* xb = x + (size_t)((base + it + 1) * 16 + lid) * D + quad * 8;
#pragma unroll
      for (int kk = 0; kk < 4; ++kk) {
        v[2 * kk]     = *(const f32x4*)(xb + kk * 32);
        v[2 * kk + 1] = *(const f32x4*)(xb + kk * 32 + 4);
      }
    }

    // MFMA: B fragments straight from LDS (conflict-floor pattern)
    f32x4 acc[4];
#pragma unroll
    for (int jt = 0; jt < 4; ++jt) acc[jt] = (f32x4){0.f, 0.f, 0.f, 0.f};
#pragma unroll
    for (int kk = 0; kk < 4; ++kk) {
#pragma unroll
      for (int jt = 0; jt < 4; ++jt) {
        short8 b = *(const short8*)(ms + (jt * 16 + lid) * MROW + kk * 32 + quad * 8);
        acc[jt] = __builtin_amdgcn_mfma_f32_16x16x32_bf16(a[kk], b, acc[jt], 0, 0, 0);
      }
    }

    // Epilogue: scores s = 2x.m - ||m||^2 bounded (|s| < ~32) -> skip max pass.
    // H = ln(S0) - S1/S0, S0 = sum e^s, S1 = sum s e^s
#pragma unroll
    for (int r = 0; r < 4; ++r) {
      float s0 = acc[0][r] - mn[0];
      float s1 = acc[1][r] - mn[1];
      float s2 = acc[2][r] - mn[2];
      float s3 = acc[3][r] - mn[3];
      float e0 = __expf(s0), e1 = __expf(s1), e2 = __expf(s2), e3 = __expf(s3);
      float S0 = (e0 + e1) + (e2 + e3);
      float S1 = fmaf(s0, e0, fmaf(s1, e1, fmaf(s2, e2, s3 * e3)));
      for (int off = 1; off < 16; off <<= 1) {
        S0 += __shfl_xor(S0, off, 64);
        S1 += __shfl_xor(S1, off, 64);
      }
      float H = __logf(S0) - S1 / S0;
      if (lid == 0) hacc += H;   // lane owns row quad*4+r
    }
  }

  // wave reduce -> block reduce -> one atomic per block
  for (int off = 1; off < 64; off <<= 1) hacc += __shfl_xor(hacc, off, 64);
  __shared__ float red[4];
  if (lane == 0) red[wv] = hacc;
  __syncthreads();
  if (tid == 0) atomicAdd(ws, red[0] + red[1] + red[2] + red[3]);
}

__global__ void final_kernel(const float* __restrict__ m, const float* ws, float* out, int nRows) {
  __shared__ float mu[D];
  int lane = threadIdx.x;  // 64 threads
  for (int d = lane; d < D; d += 64) {
    float s = 0.f;
    for (int j = 0; j < K; ++j) s += m[j * D + d];
    mu[d] = s * (1.0f / K);
  }
  __syncthreads();
  const float* mr = m + lane * D;
  float dot = 0.f;
  for (int d = 0; d < D; ++d) dot += mu[d] * mr[d];
  float s = 2.f * dot - ws[16 + lane];  // shift-invariant: drop ||mu||^2
  float t = s - 20.f;                   // safe shift
  float e = __expf(t);
  float S0 = e, S1 = t * e;
  for (int off = 1; off < 64; off <<= 1) {
    S0 += __shfl_xor(S0, off, 64);
    S1 += __shfl_xor(S1, off, 64);
  }
  float inter = __logf(S0) - S1 / S0;
  if (lane == 0) {
    float intra = ws[0] / (float)nRows;
    out[0] = intra - inter;  // LAMB = 1
    out[1] = intra;
    out[2] = inter;
  }
}

extern "C" void kernel_launch(void* const* d_in, const int* in_sizes, int n_in,
                              void* d_out, int out_size, void* d_ws, size_t ws_size,
                              hipStream_t stream) {
  const float* x = (const float*)d_in[0];
  const float* m = (const float*)d_in[1];
  float* ws = (float*)d_ws;
  float* out = (float*)d_out;
  const int N = in_sizes[0] / D;        // 262144
  const int nTiles16 = N / 16;          // 16384

  prep_kernel<<<64, 64, 0, stream>>>(m, ws);

  const int blocks = 1024;              // 4096 waves == full residency at 16 waves/CU, no tail
  const int tilesPerWave = nTiles16 / (blocks * 4);   // 4 contiguous tiles (32 KB stream) per wave
  main_kernel<<<blocks, 256, 0, stream>>>(x, ws, tilesPerWave);

  final_kernel<<<1, 64, 0, stream>>>(m, ws, out, N);
}

// Round 4
// 211.066 us; speedup vs baseline: 1.1169x; 1.0500x over previous
//
#include <hip/hip_runtime.h>
#include <hip/hip_bf16.h>

#define D 128
#define K 64
#define MROW 136   // LDS row stride in shorts: 128 + 8 pad; b128 frag reads sit at the 8-cyc floor

typedef __attribute__((ext_vector_type(8))) short short8;   // 8 bf16 in 4 VGPRs
typedef __attribute__((ext_vector_type(4))) float f32x4;

// round-to-nearest-even float -> bf16 bits (scalar path, prep only)
__device__ inline short f2bf(float f) {
  union { float f; unsigned u; } v; v.f = f;
  unsigned u = v.u;
  return (short)((u + 0x7fffu + ((u >> 16) & 1u)) >> 16);
}

// packed f32x2 -> bf16x2 (v_cvt_pk_bf16_f32 on gfx950)
__device__ inline unsigned pk2(float a, float b) {
  union { __hip_bfloat162 h; unsigned u; } c;
  c.h = __float22bfloat162_rn(make_float2(a, b));
  return c.u;
}

// ws layout (floats): [0..16) accumulator; [16..80) mnorm[64]; [128..) bf16(2*m) as 8192 shorts
__global__ void prep_kernel(const float* __restrict__ m, float* ws) {
  // 64 blocks x 64 threads: block j handles m row j
  const int j = blockIdx.x;
  const int t = threadIdx.x;
  float a0 = m[j * D + t * 2];
  float a1 = m[j * D + t * 2 + 1];
  short* mb = (short*)(ws + 128);
  mb[j * D + t * 2]     = f2bf(2.0f * a0);
  mb[j * D + t * 2 + 1] = f2bf(2.0f * a1);
  float s = a0 * a0 + a1 * a1;
  for (int off = 1; off < 64; off <<= 1) s += __shfl_xor(s, off, 64);
  if (t == 0) ws[16 + j] = s;
  if (j == 0 && t < 16) ws[t] = 0.0f;
}

// m in LDS; each wave = independent barrier-free stream over contiguous 16-row tiles.
// Pipeline per iter: convert t (packed cvt), issue t+1 loads, MFMA + epilogue.
// NOTE: no min-waves __launch_bounds__ arg — round 3 showed (256,4) caps VGPRs
// at 64 and spills 10 regs/iter to scratch (WRITE_SIZE 64B -> 39MB, convoy stalls).
__launch_bounds__(256)
__global__ void main_kernel(const float* __restrict__ x, float* ws, int tilesPerWave) {
  __shared__ short ms[64 * MROW];
  const float* mnorm = ws + 16;
  const short* mb = (const short*)(ws + 128);
  const int tid  = threadIdx.x;
  const int lane = tid & 63;
  const int wv   = tid >> 6;
  const int lid  = lane & 15;   // A row / C-D col (j)
  const int quad = lane >> 4;   // A k-group; C/D row = quad*4+reg

  const int wave = blockIdx.x * 4 + wv;
  const int base = wave * tilesPerWave;

  // Issue tile-0 x loads FIRST (longest latency), then stage m while they fly.
  f32x4 v[8];
  {
    const float* xb = x + (size_t)(base * 16 + lid) * D + quad * 8;
#pragma unroll
    for (int kk = 0; kk < 4; ++kk) {
      v[2 * kk]     = *(const f32x4*)(xb + kk * 32);
      v[2 * kk + 1] = *(const f32x4*)(xb + kk * 32 + 4);
    }
  }

  // Stage bf16(2*m) into padded LDS: each thread 4x 16B chunks (col%8==0, row-safe)
#pragma unroll
  for (int i = 0; i < 4; ++i) {
    int g = i * 2048 + tid * 8;           // short index in 64x128
    int row = g >> 7, col = g & 127;
    *(short8*)(ms + row * MROW + col) = *(const short8*)(mb + g);
  }
  float mn[4];
#pragma unroll
  for (int jt = 0; jt < 4; ++jt) mn[jt] = mnorm[jt * 16 + lid];
  __syncthreads();   // the only block-wide barrier

  float hacc = 0.f;

  for (int it = 0; it < tilesPerWave; ++it) {
    // Convert current tile to A fragments via packed cvt (frees v for reuse)
    short8 a[4];
#pragma unroll
    for (int kk = 0; kk < 4; ++kk) {
      f32x4 v0 = v[2 * kk], v1 = v[2 * kk + 1];
      union { short8 s; unsigned u[4]; } av;
      av.u[0] = pk2(v0[0], v0[1]);
      av.u[1] = pk2(v0[2], v0[3]);
      av.u[2] = pk2(v1[0], v1[1]);
      av.u[3] = pk2(v1[2], v1[3]);
      a[kk] = av.s;
    }

    // Issue next tile's loads now; they stay in flight through MFMA + epilogue
    if (it + 1 < tilesPerWave) {
      const float* xb = x + (size_t)((base + it + 1) * 16 + lid) * D + quad * 8;
#pragma unroll
      for (int kk = 0; kk < 4; ++kk) {
        v[2 * kk]     = *(const f32x4*)(xb + kk * 32);
        v[2 * kk + 1] = *(const f32x4*)(xb + kk * 32 + 4);
      }
    }

    // MFMA: B fragments straight from LDS (bank-floor pattern)
    f32x4 acc[4];
#pragma unroll
    for (int jt = 0; jt < 4; ++jt) acc[jt] = (f32x4){0.f, 0.f, 0.f, 0.f};
#pragma unroll
    for (int kk = 0; kk < 4; ++kk) {
#pragma unroll
      for (int jt = 0; jt < 4; ++jt) {
        short8 b = *(const short8*)(ms + (jt * 16 + lid) * MROW + kk * 32 + quad * 8);
        acc[jt] = __builtin_amdgcn_mfma_f32_16x16x32_bf16(a[kk], b, acc[jt], 0, 0, 0);
      }
    }

    // Epilogue: scores s = 2x.m - ||m||^2 bounded (|s| < ~32) -> skip max pass.
    // H = ln(S0) - S1/S0, S0 = sum e^s, S1 = sum s e^s
#pragma unroll
    for (int r = 0; r < 4; ++r) {
      float s0 = acc[0][r] - mn[0];
      float s1 = acc[1][r] - mn[1];
      float s2 = acc[2][r] - mn[2];
      float s3 = acc[3][r] - mn[3];
      float e0 = __expf(s0), e1 = __expf(s1), e2 = __expf(s2), e3 = __expf(s3);
      float S0 = (e0 + e1) + (e2 + e3);
      float S1 = fmaf(s0, e0, fmaf(s1, e1, fmaf(s2, e2, s3 * e3)));
      for (int off = 1; off < 16; off <<= 1) {
        S0 += __shfl_xor(S0, off, 64);
        S1 += __shfl_xor(S1, off, 64);
      }
      float H = __logf(S0) - S1 / S0;
      if (lid == 0) hacc += H;   // lane owns row quad*4+r
    }
  }

  // wave reduce -> block reduce -> one atomic per block
  for (int off = 1; off < 64; off <<= 1) hacc += __shfl_xor(hacc, off, 64);
  __shared__ float red[4];
  if (lane == 0) red[wv] = hacc;
  __syncthreads();
  if (tid == 0) atomicAdd(ws, red[0] + red[1] + red[2] + red[3]);
}

__global__ void final_kernel(const float* __restrict__ m, const float* ws, float* out, int nRows) {
  __shared__ float mu[D];
  int lane = threadIdx.x;  // 64 threads
  for (int d = lane; d < D; d += 64) {
    float s = 0.f;
    for (int j = 0; j < K; ++j) s += m[j * D + d];
    mu[d] = s * (1.0f / K);
  }
  __syncthreads();
  const float* mr = m + lane * D;
  float dot = 0.f;
  for (int d = 0; d < D; ++d) dot += mu[d] * mr[d];
  float s = 2.f * dot - ws[16 + lane];  // shift-invariant: drop ||mu||^2
  float t = s - 20.f;                   // safe shift
  float e = __expf(t);
  float S0 = e, S1 = t * e;
  for (int off = 1; off < 64; off <<= 1) {
    S0 += __shfl_xor(S0, off, 64);
    S1 += __shfl_xor(S1, off, 64);
  }
  float inter = __logf(S0) - S1 / S0;
  if (lane == 0) {
    float intra = ws[0] / (float)nRows;
    out[0] = intra - inter;  // LAMB = 1
    out[1] = intra;
    out[2] = inter;
  }
}

extern "C" void kernel_launch(void* const* d_in, const int* in_sizes, int n_in,
                              void* d_out, int out_size, void* d_ws, size_t ws_size,
                              hipStream_t stream) {
  const float* x = (const float*)d_in[0];
  const float* m = (const float*)d_in[1];
  float* ws = (float*)d_ws;
  float* out = (float*)d_out;
  const int N = in_sizes[0] / D;        // 262144
  const int nTiles16 = N / 16;          // 16384

  prep_kernel<<<64, 64, 0, stream>>>(m, ws);

  const int blocks = 1024;              // 4096 waves, 4 contiguous 16-row tiles each
  const int tilesPerWave = nTiles16 / (blocks * 4);
  main_kernel<<<blocks, 256, 0, stream>>>(x, ws, tilesPerWave);

  final_kernel<<<1, 64, 0, stream>>>(m, ws, out, N);
}